// Round 4
// baseline (18.706 us; speedup 1.0000x reference)
//
#include <hip/hip_runtime.h>

// Paste2dMulti: N=64, M=8, C=3, H=W=64, canvas l=256.
// Gather form. Thread = one output column x 4-row vertical strip.
// Branch-free inner body: source col clamped, invalid lanes zeroed via
// cndmask folded into the x-mask -> all surviving-m loads issue in one
// burst (single vmcnt wait), no divergent branches around loads.
// 32-bit offsets + per-channel base pointers so row loads use the 13-bit
// immediate offset (k*256B), minimizing 64-bit address math.

__device__ __forceinline__ float clamp01(float v) {
    return fminf(fmaxf(v, 0.0f), 1.0f);   // -> v_med3_f32
}

__global__ __launch_bounds__(256) void Paste2dMulti_kernel(
    const float* __restrict__ coords,   // [64][8][4]
    const float* __restrict__ images,   // [64][8][3][64][64]
    float* __restrict__ out)            // [64][1][256][256]
{
    const int bid  = blockIdx.x;       // 64 n * 64 bands
    const int n    = bid >> 6;         // block-uniform
    const int band = bid & 63;
    const int col  = threadIdx.x;      // 0..255; wave covers 64 consecutive cols
    const int r0   = band * 4;         // rows r0 .. r0+3

    const float fc = (float)col;
    const float* cb = coords + n * 32;
    const float* ib = images + (size_t)n * (8 * 3 * 4096);

    float acc0 = 0.f, acc1 = 0.f, acc2 = 0.f, acc3 = 0.f;

    #pragma unroll
    for (int m = 0; m < 8; ++m) {
        const float c1  = cb[m * 4 + 1];
        const int   y0  = (int)c1;         // trunc (coords >= 0)
        const int   srl = r0 - y0;         // source row of band row 0
        if (srl + 3 < 0 || srl >= 64) continue;   // wave-uniform skip (~6/8 m)

        const float c0 = cb[m * 4 + 0];
        const float c2 = cb[m * 4 + 2];
        const float c3 = cb[m * 4 + 3];

        const int  x0    = (int)c0;
        const int  sc    = col - x0;
        const bool valid = (unsigned)sc < 64u;
        const int  scc   = min(max(sc, 0), 63);       // clamped -> always legal

        float xm = clamp01(fc - c0 + 1.f) * clamp01(c2 + 1.f - fc);
        xm = valid ? xm : 0.f;                        // one v_cndmask, no branch

        // Per-channel base addresses; rows via 256B immediate offsets.
        const int base = m * (3 * 4096) + srl * 64 + scc;   // 32-bit elem offset
        const float* q0 = ib + base;
        const float* q1 = q0 + 4096;
        const float* q2 = q0 + 8192;

        #pragma unroll
        for (int k = 0; k < 4; ++k) {
            const int sr = srl + k;                   // wave-uniform validity
            if (sr < 0 || sr >= 64) continue;         // scalar branch
            const float fr = (float)(r0 + k);
            const float ym = clamp01(fr - c1 + 1.f) * clamp01(c3 + 1.f - fr);
            const float s  = q0[k * 64] + q1[k * 64] + q2[k * 64];
            const float wgt = xm * ym;
            if (k == 0) acc0 = fmaf(wgt, s, acc0);
            if (k == 1) acc1 = fmaf(wgt, s, acc1);
            if (k == 2) acc2 = fmaf(wgt, s, acc2);
            if (k == 3) acc3 = fmaf(wgt, s, acc3);
        }
    }

    float* o = out + (size_t)n * 65536 + (size_t)r0 * 256 + col;
    o[0]   = fminf(1.f, acc0);
    o[256] = fminf(1.f, acc1);
    o[512] = fminf(1.f, acc2);
    o[768] = fminf(1.f, acc3);
}

extern "C" void kernel_launch(void* const* d_in, const int* in_sizes, int n_in,
                              void* d_out, int out_size, void* d_ws, size_t ws_size,
                              hipStream_t stream) {
    const float* coords = (const float*)d_in[0];
    const float* images = (const float*)d_in[1];
    float* out = (float*)d_out;

    // 64 batches * 64 bands of 4 rows; 256 threads = one column each.
    Paste2dMulti_kernel<<<64 * 64, 256, 0, stream>>>(coords, images, out);
}